// Round 1
// baseline (516.978 us; speedup 1.0000x reference)
//
#include <hip/hip_runtime.h>
#include <math.h>

// Problem constants
#define NB 4
#define NC 2048
#define NH 8
#define NK 128

// exp2-domain logit scale: log2(e)/sqrt(128)
#define A2SCALE (1.4426950408889634f * 0.08838834764831845f)

// ---------------- ws layout (float offsets) ----------------
// wqsum  [8][128]         @ 0        (1024)
// wksum  [8][128]         @ 1024     (1024)
// W2     [8][128][128]    @ 2048     (131072)
// qs     [32][2048]       @ 133120   (65536)   ([b*8+h][t])
// ks     [32][2048]       @ 198656   (65536)
// kmn    [32]             @ 264192
// kmx    [32]             @ 264224
// u      [32][2048][128]  @ 264256   (8388608) ([b*8+h][i][kk])
// total: 8652864 floats = 34.6 MB
#define OFF_W2  2048
#define OFF_QS  133120
#define OFF_KS  198656
#define OFF_KMN 264192
#define OFF_KMX 264224
#define OFF_U   264256

// wqsum[h][m] = sum_e Wq[h*128+e][m]; same for k.  grid 8 x 256
__global__ __launch_bounds__(256) void k_wsum(const float* __restrict__ Wq,
                                              const float* __restrict__ Wk,
                                              float* __restrict__ ws) {
    int id = blockIdx.x * 256 + threadIdx.x;   // 0..2047
    int which = id >> 10;
    int hm = id & 1023;
    const float* W = which ? Wk : Wq;
    int h = hm >> 7, m = hm & 127;
    const float* base = W + (h * 128) * 128 + m;
    float s = 0.f;
#pragma unroll 4
    for (int e = 0; e < 128; ++e) s += base[e * 128];
    ws[which * 1024 + hm] = s;
}

// W2[h][kk][m] = sum_e Wv[h*128+e][m] * Wo[kk][h*128+e].  grid 1024 x 128
__global__ __launch_bounds__(128) void k_w2(const float* __restrict__ Wv,
                                            const float* __restrict__ Wo,
                                            float* __restrict__ W2) {
    int h = blockIdx.x >> 7, kk = blockIdx.x & 127;
    __shared__ float wo_s[128];
    int m = threadIdx.x;
    wo_s[m] = Wo[kk * 1024 + h * 128 + m];
    __syncthreads();
    const float* base = Wv + (h * 128) * 128 + m;
    float s = 0.f;
#pragma unroll 4
    for (int e = 0; e < 128; ++e) s += base[e * 128] * wo_s[e];
    W2[(h * 128 + kk) * 128 + m] = s;
}

// qs[bh][t], ks[bh][t].  grid 256 x 256 (32 rows per block)
__global__ __launch_bounds__(256) void k_qsks(const float* __restrict__ x,
                                              const float* __restrict__ ws,
                                              float* __restrict__ qs,
                                              float* __restrict__ ks) {
    __shared__ float xs[32][129];
    __shared__ float wsum[2048];   // [which][h][m]
    int tid = threadIdx.x;
    for (int j = tid; j < 2048; j += 256) wsum[j] = ws[j];
    int row0 = blockIdx.x * 32;
    for (int j = tid; j < 32 * 128; j += 256) {
        int r = j >> 7, m = j & 127;
        xs[r][m] = x[(size_t)(row0 + r) * 128 + m];
    }
    __syncthreads();
#pragma unroll
    for (int jj = 0; jj < 2; ++jj) {
        int o = tid + 256 * jj;
        int r = o & 31;
        int q = o >> 5;                 // 0..15
        int which = q >> 3, h = q & 7;
        const float* wrow = &wsum[which * 1024 + h * 128];
        float s = 0.f;
#pragma unroll 4
        for (int m = 0; m < 128; ++m) s += xs[r][m] * wrow[m];
        int row = row0 + r, b = row >> 11, t = row & 2047;
        float* dst = which ? ks : qs;
        dst[(b * 8 + h) * 2048 + t] = s;
    }
}

// per-(b,h) min/max of ks.  grid 32 x 256
__global__ __launch_bounds__(256) void k_minmax(const float* __restrict__ ks,
                                                float* __restrict__ kmn,
                                                float* __restrict__ kmx) {
    int bh = blockIdx.x;
    const float* kr = ks + bh * 2048;
    float mn = 1e30f, mx = -1e30f;
    for (int j = threadIdx.x; j < 2048; j += 256) {
        float v = kr[j];
        mn = fminf(mn, v);
        mx = fmaxf(mx, v);
    }
#pragma unroll
    for (int off = 32; off; off >>= 1) {
        mn = fminf(mn, __shfl_xor(mn, off));
        mx = fmaxf(mx, __shfl_xor(mx, off));
    }
    __shared__ float smn[4], smx[4];
    int w = threadIdx.x >> 6;
    if ((threadIdx.x & 63) == 0) { smn[w] = mn; smx[w] = mx; }
    __syncthreads();
    if (threadIdx.x == 0) {
        mn = fminf(fminf(smn[0], smn[1]), fminf(smn[2], smn[3]));
        mx = fmaxf(fmaxf(smx[0], smx[1]), fmaxf(smx[2], smx[3]));
        kmn[bh] = mn;
        kmx[bh] = mx;
    }
}

// u[bh][i][kk] = sum_m x[b][i][m] * W2[h][kk][m].  grid 512 x 256
// block = (b,h, i-tile of 128). 128x128 out tile, m-chunks of 32.
__global__ __launch_bounds__(256) void k_ugemm(const float* __restrict__ x,
                                               const float* __restrict__ W2,
                                               float* __restrict__ u) {
    int gid = blockIdx.x;
    int b = gid >> 7, h = (gid >> 4) & 7, it = gid & 15;
    __shared__ float xs[128][32];    // [i][m], f4-block XOR swizzled by (i>>3)
    __shared__ float w2s[128][32];   // [kk][m], f4-block XOR swizzled by (kk)
    int tid = threadIdx.x;
    int tr = tid >> 4, tc = tid & 15;   // i = tr*8+rt ; kk = tc + 16*ck
    float acc[8][8] = {};
    const float* xb = x + (size_t)(b * 2048 + it * 128) * 128;
    const float* w2h = W2 + h * 128 * 128;

    for (int mc = 0; mc < 128; mc += 32) {
        for (int j = tid; j < 1024; j += 256) {
            int r = j >> 3, c4 = j & 7;
            float4 vx = *(const float4*)&xb[r * 128 + mc + c4 * 4];
            float4 vw = *(const float4*)&w2h[r * 128 + mc + c4 * 4];
            ((float4*)xs[r])[c4 ^ ((r >> 3) & 7)] = vx;
            ((float4*)w2s[r])[c4 ^ (r & 7)] = vw;
        }
        __syncthreads();
#pragma unroll 2
        for (int m = 0; m < 32; ++m) {
            int mc4 = m >> 2, mr = m & 3;
            float xv[8], wv[8];
#pragma unroll
            for (int rt = 0; rt < 8; ++rt) {
                int i = tr * 8 + rt;
                xv[rt] = xs[i][((mc4 ^ ((i >> 3) & 7)) << 2) + mr];
            }
#pragma unroll
            for (int ck = 0; ck < 8; ++ck) {
                int kk = tc + ck * 16;
                wv[ck] = w2s[kk][((mc4 ^ (kk & 7)) << 2) + mr];
            }
#pragma unroll
            for (int rt = 0; rt < 8; ++rt)
#pragma unroll
                for (int ck = 0; ck < 8; ++ck)
                    acc[rt][ck] = fmaf(xv[rt], wv[ck], acc[rt][ck]);
        }
        __syncthreads();
    }
    float* ub = u + (size_t)((b * 8 + h) * 2048 + it * 128) * 128;
#pragma unroll
    for (int rt = 0; rt < 8; ++rt)
#pragma unroll
        for (int ck = 0; ck < 8; ++ck)
            ub[(tr * 8 + rt) * 128 + tc + ck * 16] = acc[rt][ck];
}

// init d_out with bias.  grid 1024 x 256, float4
__global__ __launch_bounds__(256) void k_bias(const float* __restrict__ bo,
                                              float* __restrict__ y) {
    int id = blockIdx.x * 256 + threadIdx.x;   // 0..262143 float4s
    int kk4 = id & 31;
    ((float4*)y)[id] = ((const float4*)bo)[kk4];
}

// attention + output: y[b][t][kk] += sum_h (1/z) sum_i w(t,i) * u[bh][i][kk]
// grid 512 x 256. block = (bh, t-tile of 128). XCD-locality mapping.
__global__ __launch_bounds__(256) void k_attn(const float* __restrict__ qs,
                                              const float* __restrict__ ks,
                                              const float* __restrict__ kmn,
                                              const float* __restrict__ kmx,
                                              const float* __restrict__ u,
                                              float* __restrict__ y) {
    int L = blockIdx.x;
    int xcd = L & 7, slot = L >> 3;
    int bh = xcd * 4 + (slot >> 4);   // 4 bh groups per XCD -> u slice (4MB) L2-resident
    int tt = slot & 15;
    int b = bh >> 3;
    int t0 = tt * 128;
    int tid = threadIdx.x;
    int tr = tid >> 4, tc = tid & 15;   // t_local = tr*8+rt ; kk = tc + 16*ck

    __shared__ float us[32][128];       // u chunk [i][kk]
    __shared__ float wt2[32][128];      // weights [i][t]
    __shared__ float kss[2048];
    __shared__ float ats[128];
    __shared__ float Ms[128];
    __shared__ float zp[128][2];
    __shared__ float zs[128];

    for (int j = tid; j < 2048; j += 256) kss[j] = ks[bh * 2048 + j];
    if (tid < 128) {
        float a = qs[bh * 2048 + t0 + tid] * A2SCALE;
        float kn = kmn[bh], kx = kmx[bh];
        ats[tid] = a;
        Ms[tid] = a > 0.f ? a * kx : a * kn;
    }
    zp[tid >> 1][tid & 1] = 0.f;

    float acc[8][8] = {};
    int twt = tid >> 1, half = tid & 1;

    for (int ic = 0; ic < 2048; ic += 32) {
        __syncthreads();   // protect us/wt2 from previous iteration's readers
        // stage u chunk (32 x 128 floats)
        for (int j = tid; j < 1024; j += 256) {
            int r = j >> 5, c4 = j & 31;
            ((float4*)us[r])[c4] =
                *(const float4*)&u[(size_t)(bh * 2048 + ic + r) * 128 + c4 * 4];
        }
        // weight tile: thread (twt, half) computes w[t=twt][i=ic+half*16+q]
        {
            float a = ats[twt], M = Ms[twt];
            float zacc = 0.f;
#pragma unroll
            for (int q = 0; q < 16; ++q) {
                float w = exp2f(fmaf(a, kss[ic + half * 16 + q], -M));
                wt2[half * 16 + q][twt] = w;
                zacc += w;
            }
            zp[twt][half] += zacc;
        }
        __syncthreads();
#pragma unroll 2
        for (int i = 0; i < 32; ++i) {
            float4 wa = *(float4*)&wt2[i][tr * 8];
            float4 wb = *(float4*)&wt2[i][tr * 8 + 4];
            float wv[8] = {wa.x, wa.y, wa.z, wa.w, wb.x, wb.y, wb.z, wb.w};
            float uv[8];
#pragma unroll
            for (int ck = 0; ck < 8; ++ck) uv[ck] = us[i][ck * 16 + tc];
#pragma unroll
            for (int rt = 0; rt < 8; ++rt)
#pragma unroll
                for (int ck = 0; ck < 8; ++ck)
                    acc[rt][ck] = fmaf(wv[rt], uv[ck], acc[rt][ck]);
        }
    }
    __syncthreads();
    if (tid < 128) zs[tid] = zp[tid][0] + zp[tid][1];
    __syncthreads();

#pragma unroll
    for (int rt = 0; rt < 8; ++rt) {
        int tl = tr * 8 + rt;
        float zinv = 1.f / zs[tl];
        float* yrow = y + (size_t)(b * 2048 + t0 + tl) * 128;
#pragma unroll
        for (int ck = 0; ck < 8; ++ck)
            atomicAdd(&yrow[ck * 16 + tc], acc[rt][ck] * zinv);
    }
}

extern "C" void kernel_launch(void* const* d_in, const int* in_sizes, int n_in,
                              void* d_out, int out_size, void* d_ws, size_t ws_size,
                              hipStream_t stream) {
    const float* x  = (const float*)d_in[0];
    const float* Wq = (const float*)d_in[1];
    const float* Wk = (const float*)d_in[2];
    const float* Wv = (const float*)d_in[3];
    const float* Wo = (const float*)d_in[4];
    const float* bo = (const float*)d_in[5];
    float* y  = (float*)d_out;
    float* ws = (float*)d_ws;
    (void)in_sizes; (void)n_in; (void)out_size; (void)ws_size;

    k_wsum<<<8, 256, 0, stream>>>(Wq, Wk, ws);
    k_w2<<<1024, 128, 0, stream>>>(Wv, Wo, ws + OFF_W2);
    k_qsks<<<256, 256, 0, stream>>>(x, ws, ws + OFF_QS, ws + OFF_KS);
    k_minmax<<<32, 256, 0, stream>>>(ws + OFF_KS, ws + OFF_KMN, ws + OFF_KMX);
    k_ugemm<<<512, 256, 0, stream>>>(x, ws + OFF_W2, ws + OFF_U);
    k_bias<<<1024, 256, 0, stream>>>(bo, y);
    k_attn<<<512, 256, 0, stream>>>(ws + OFF_QS, ws + OFF_KS, ws + OFF_KMN,
                                    ws + OFF_KMX, ws + OFF_U, y);
}

// Round 2
// 163.216 us; speedup vs baseline: 3.1675x; 3.1675x over previous
//
#include <hip/hip_runtime.h>
#include <math.h>

// Problem constants
#define NB 4
#define NC 2048
#define NH 8
#define NK 128

// exp2-domain logit scale: log2(e)/sqrt(128)
#define A2SCALE (1.4426950408889634f * 0.08838834764831845f)

typedef __attribute__((ext_vector_type(8))) short bf16x8;
typedef __attribute__((ext_vector_type(4))) float f32x4;

// ---------------- ws layout (float offsets) ----------------
// wqsum  [8][128]         @ 0
// wksum  [8][128]         @ 1024
// W2     [8][128][128]    @ 2048
// qs     [32][2048]       @ 133120
// ks     [32][2048]       @ 198656
// kmn    [32]             @ 264192
// kmx    [32]             @ 264224
// u(bf16)[32][64ic][8nt][64lane][8j] @ 264256  (8.39M ushort = 16.8 MB)
#define OFF_W2  2048
#define OFF_QS  133120
#define OFF_KS  198656
#define OFF_KMN 264192
#define OFF_KMX 264224
#define OFF_U   264256

__device__ static inline unsigned short f2bf(float f) {
    unsigned u = __float_as_uint(f);
    return (unsigned short)((u + 0x7FFFu + ((u >> 16) & 1u)) >> 16);
}

// wqsum[h][m] = sum_e Wq[h*128+e][m]; same for k.  grid 8 x 256
__global__ __launch_bounds__(256) void k_wsum(const float* __restrict__ Wq,
                                              const float* __restrict__ Wk,
                                              float* __restrict__ ws) {
    int id = blockIdx.x * 256 + threadIdx.x;   // 0..2047
    int which = id >> 10;
    int hm = id & 1023;
    const float* W = which ? Wk : Wq;
    int h = hm >> 7, m = hm & 127;
    const float* base = W + (h * 128) * 128 + m;
    float s = 0.f;
#pragma unroll 4
    for (int e = 0; e < 128; ++e) s += base[e * 128];
    ws[which * 1024 + hm] = s;
}

// W2[h][kk][m] = sum_e Wv[h*128+e][m] * Wo[kk][h*128+e].  grid 1024 x 128
__global__ __launch_bounds__(128) void k_w2(const float* __restrict__ Wv,
                                            const float* __restrict__ Wo,
                                            float* __restrict__ W2) {
    int h = blockIdx.x >> 7, kk = blockIdx.x & 127;
    __shared__ float wo_s[128];
    int m = threadIdx.x;
    wo_s[m] = Wo[kk * 1024 + h * 128 + m];
    __syncthreads();
    const float* base = Wv + (h * 128) * 128 + m;
    float s = 0.f;
#pragma unroll 4
    for (int e = 0; e < 128; ++e) s += base[e * 128] * wo_s[e];
    W2[(h * 128 + kk) * 128 + m] = s;
}

// qs[bh][t], ks[bh][t].  grid 256 x 256 (32 rows per block)
__global__ __launch_bounds__(256) void k_qsks(const float* __restrict__ x,
                                              const float* __restrict__ ws,
                                              float* __restrict__ qs,
                                              float* __restrict__ ks) {
    __shared__ float xs[32][129];
    __shared__ float wsum[2048];
    int tid = threadIdx.x;
    for (int j = tid; j < 2048; j += 256) wsum[j] = ws[j];
    int row0 = blockIdx.x * 32;
    for (int j = tid; j < 32 * 128; j += 256) {
        int r = j >> 7, m = j & 127;
        xs[r][m] = x[(size_t)(row0 + r) * 128 + m];
    }
    __syncthreads();
#pragma unroll
    for (int jj = 0; jj < 2; ++jj) {
        int o = tid + 256 * jj;
        int r = o & 31;
        int q = o >> 5;
        int which = q >> 3, h = q & 7;
        const float* wrow = &wsum[which * 1024 + h * 128];
        float s = 0.f;
#pragma unroll 4
        for (int m = 0; m < 128; ++m) s += xs[r][m] * wrow[m];
        int row = row0 + r, b = row >> 11, t = row & 2047;
        float* dst = which ? ks : qs;
        dst[(b * 8 + h) * 2048 + t] = s;
    }
}

// per-(b,h) min/max of ks.  grid 32 x 256
__global__ __launch_bounds__(256) void k_minmax(const float* __restrict__ ks,
                                                float* __restrict__ kmn,
                                                float* __restrict__ kmx) {
    int bh = blockIdx.x;
    const float* kr = ks + bh * 2048;
    float mn = 1e30f, mx = -1e30f;
    for (int j = threadIdx.x; j < 2048; j += 256) {
        float v = kr[j];
        mn = fminf(mn, v);
        mx = fmaxf(mx, v);
    }
#pragma unroll
    for (int off = 32; off; off >>= 1) {
        mn = fminf(mn, __shfl_xor(mn, off));
        mx = fmaxf(mx, __shfl_xor(mx, off));
    }
    __shared__ float smn[4], smx[4];
    int w = threadIdx.x >> 6;
    if ((threadIdx.x & 63) == 0) { smn[w] = mn; smx[w] = mx; }
    __syncthreads();
    if (threadIdx.x == 0) {
        mn = fminf(fminf(smn[0], smn[1]), fminf(smn[2], smn[3]));
        mx = fmaxf(fmaxf(smx[0], smx[1]), fmaxf(smx[2], smx[3]));
        kmn[bh] = mn;
        kmx[bh] = mx;
    }
}

// u[bh][i][kk] = sum_m x[b][i][m] * W2[h][kk][m], stored bf16 in MFMA-B-frag
// layout: ub[bh][ic32][nt][lane][j].  grid 512 x 256
__global__ __launch_bounds__(256) void k_ugemm(const float* __restrict__ x,
                                               const float* __restrict__ W2,
                                               unsigned short* __restrict__ u16) {
    int gid = blockIdx.x;
    int b = gid >> 7, h = (gid >> 4) & 7, it = gid & 15;
    __shared__ float xs[128][32];
    __shared__ float w2s[128][32];
    int tid = threadIdx.x;
    int tr = tid >> 4, tc = tid & 15;   // i_local = tr*8+rt ; kk = tc + 16*ck
    float acc[8][8] = {};
    const float* xb = x + (size_t)(b * 2048 + it * 128) * 128;
    const float* w2h = W2 + h * 128 * 128;

    for (int mc = 0; mc < 128; mc += 32) {
        for (int j = tid; j < 1024; j += 256) {
            int r = j >> 3, c4 = j & 7;
            float4 vx = *(const float4*)&xb[r * 128 + mc + c4 * 4];
            float4 vw = *(const float4*)&w2h[r * 128 + mc + c4 * 4];
            ((float4*)xs[r])[c4 ^ ((r >> 3) & 7)] = vx;
            ((float4*)w2s[r])[c4 ^ (r & 7)] = vw;
        }
        __syncthreads();
#pragma unroll 2
        for (int m = 0; m < 32; ++m) {
            int mc4 = m >> 2, mr = m & 3;
            float xv[8], wv[8];
#pragma unroll
            for (int rt = 0; rt < 8; ++rt) {
                int i = tr * 8 + rt;
                xv[rt] = xs[i][((mc4 ^ ((i >> 3) & 7)) << 2) + mr];
            }
#pragma unroll
            for (int ck = 0; ck < 8; ++ck) {
                int kk = tc + ck * 16;
                wv[ck] = w2s[kk][((mc4 ^ (kk & 7)) << 2) + mr];
            }
#pragma unroll
            for (int rt = 0; rt < 8; ++rt)
#pragma unroll
                for (int ck = 0; ck < 8; ++ck)
                    acc[rt][ck] = fmaf(xv[rt], wv[ck], acc[rt][ck]);
        }
        __syncthreads();
    }
    // epilogue: bf16 B-fragment layout. For this thread all 8 rt of a ck are
    // contiguous j's at one (ic32, nt, lane):
    //   ic32 = it*4 + (tr>>2), nt = ck, lane = tc + ((tr&3)<<4), j = rt
    unsigned short* ub = u16 + (size_t)(b * 8 + h) * 64 * 4096;
#pragma unroll
    for (int ck = 0; ck < 8; ++ck) {
        union { unsigned short us[8]; uint4 v; } pk;
#pragma unroll
        for (int rt = 0; rt < 8; ++rt) pk.us[rt] = f2bf(acc[rt][ck]);
        size_t idx = ((size_t)(it * 4 + (tr >> 2)) * 8 + ck) * 512 +
                     (tc + ((tr & 3) << 4)) * 8;
        *(uint4*)&ub[idx] = pk.v;
    }
}

// init d_out with bias.  grid 1024 x 256, float4
__global__ __launch_bounds__(256) void k_bias(const float* __restrict__ bo,
                                              float* __restrict__ y) {
    int id = blockIdx.x * 256 + threadIdx.x;
    int kk4 = id & 31;
    ((float4*)y)[id] = ((const float4*)bo)[kk4];
}

// attention + output via MFMA: y[b][t][kk] += (1/z_t) sum_i P[t,i] * u[i,kk]
// grid 512 x 256 (bh x 16 t-tiles of 128), XCD-locality mapping.
__global__ __launch_bounds__(256) void k_attn(const float* __restrict__ qs,
                                              const float* __restrict__ ks,
                                              const float* __restrict__ kmn,
                                              const float* __restrict__ kmx,
                                              const unsigned short* __restrict__ ub,
                                              float* __restrict__ y) {
    int L = blockIdx.x;
    int xcd = L & 7, slot = L >> 3;
    int bh = xcd * 4 + (slot >> 4);   // 4 bh per XCD -> u slice (2MB bf16) L2-resident
    int tt = slot & 15;
    int b = bh >> 3;
    int t0 = tt * 128;
    int tid = threadIdx.x;
    int lane = tid & 63, wid = tid >> 6;
    int wr = wid >> 1, wc = wid & 1;   // wave covers t in [wr*64,+64), kk in [wc*64,+64)

    __shared__ uint4 p_lds4[1024];   // P bf16, A-frag layout [ks2][mt8][lane64][j8]
    __shared__ uint4 u_lds4[1024];   // u bf16, B-frag layout [ks2][nt8][lane64][j8]
    __shared__ float kss[2048];
    __shared__ float zp[128][2];
    __shared__ float zs[128];

    for (int j = tid; j < 512; j += 256)
        ((float4*)kss)[j] = ((const float4*)(ks + bh * 2048))[j];

    int t = tid >> 1, hf = tid & 1;    // this thread computes P row t, i-half hf
    float a = qs[bh * 2048 + t0 + t] * A2SCALE;
    float kn = kmn[bh], kx = kmx[bh];
    float M = a > 0.f ? a * kx : a * kn;   // exact row max (rank-1 logits)
    float zacc = 0.f;

    const unsigned short* gub = ub + (size_t)bh * 64 * 4096;
    f32x4 acc[4][4];
#pragma unroll
    for (int m = 0; m < 4; ++m)
#pragma unroll
        for (int n = 0; n < 4; ++n) acc[m][n] = (f32x4)0.f;

    int pb = (hf * 8 + (t >> 4)) * 64 + (t & 15);   // uint4 index base in p_lds4

    for (int ic = 0; ic < 2048; ic += 64) {
        __syncthreads();   // protect LDS from previous iteration's readers
        // ---- stage u chunk (16 KB, linear) via async global->LDS ----
        {
            const unsigned short* src = gub + (size_t)(ic >> 5) * 4096;
#pragma unroll
            for (int s = 0; s < 4; ++s) {
                int seg = s * 4 + wid;   // wave-uniform
                __builtin_amdgcn_global_load_lds(
                    (const __attribute__((address_space(1))) unsigned int*)(src + seg * 512 + lane * 8),
                    (__attribute__((address_space(3))) unsigned int*)((unsigned short*)u_lds4 + seg * 512),
                    16, 0, 0);
            }
        }
        // ---- compute P tile 128x64 -> bf16 A-frags in LDS ----
        {
            const float* kp = &kss[ic + hf * 32];
            unsigned words[16];
#pragma unroll
            for (int q = 0; q < 16; ++q) {
                float w0 = exp2f(fmaf(a, kp[2 * q], -M));
                float w1 = exp2f(fmaf(a, kp[2 * q + 1], -M));
                zacc += w0 + w1;
                // pack 2 f32 -> 2 bf16 (round-half-up) in one v_perm
                words[q] = __builtin_amdgcn_perm(__float_as_uint(w1) + 0x8000u,
                                                 __float_as_uint(w0) + 0x8000u,
                                                 0x07060302u);
            }
#pragma unroll
            for (int g = 0; g < 4; ++g)
                p_lds4[pb + g * 16] =
                    make_uint4(words[4 * g], words[4 * g + 1], words[4 * g + 2], words[4 * g + 3]);
        }
        __syncthreads();   // drains vmcnt (u ready) + lgkm (P ready)
        // ---- MFMA phase: 2 k-steps of 32, 16 mfma each ----
#pragma unroll
        for (int kq = 0; kq < 2; ++kq) {
            bf16x8 af[4], bfr[4];
#pragma unroll
            for (int m = 0; m < 4; ++m)
                af[m] = *(const bf16x8*)&p_lds4[(kq * 8 + wr * 4 + m) * 64 + lane];
#pragma unroll
            for (int n = 0; n < 4; ++n)
                bfr[n] = *(const bf16x8*)&u_lds4[(kq * 8 + wc * 4 + n) * 64 + lane];
#pragma unroll
            for (int m = 0; m < 4; ++m)
#pragma unroll
                for (int n = 0; n < 4; ++n)
                    acc[m][n] = __builtin_amdgcn_mfma_f32_16x16x32_bf16(
                        af[m], bfr[n], acc[m][n], 0, 0, 0);
        }
    }
    __syncthreads();
    zp[t][hf] = zacc;
    __syncthreads();
    if (tid < 128) zs[tid] = 1.f / (zp[tid][0] + zp[tid][1]);
    __syncthreads();

    // epilogue: C/D layout col=lane&15, row=(lane>>4)*4+reg
    int l16 = lane & 15, l4 = lane >> 4;
#pragma unroll
    for (int m = 0; m < 4; ++m) {
#pragma unroll
        for (int r = 0; r < 4; ++r) {
            int tl = wr * 64 + m * 16 + l4 * 4 + r;
            float zinv = zs[tl];
            float* yrow = y + ((size_t)b * 2048 + t0 + tl) * 128;
#pragma unroll
            for (int n = 0; n < 4; ++n)
                atomicAdd(&yrow[wc * 64 + n * 16 + l16], acc[m][n][r] * zinv);
        }
    }
}

extern "C" void kernel_launch(void* const* d_in, const int* in_sizes, int n_in,
                              void* d_out, int out_size, void* d_ws, size_t ws_size,
                              hipStream_t stream) {
    const float* x  = (const float*)d_in[0];
    const float* Wq = (const float*)d_in[1];
    const float* Wk = (const float*)d_in[2];
    const float* Wv = (const float*)d_in[3];
    const float* Wo = (const float*)d_in[4];
    const float* bo = (const float*)d_in[5];
    float* y  = (float*)d_out;
    float* ws = (float*)d_ws;
    (void)in_sizes; (void)n_in; (void)out_size; (void)ws_size;

    unsigned short* u16 = (unsigned short*)(ws + OFF_U);

    k_wsum<<<8, 256, 0, stream>>>(Wq, Wk, ws);
    k_w2<<<1024, 128, 0, stream>>>(Wv, Wo, ws + OFF_W2);
    k_qsks<<<256, 256, 0, stream>>>(x, ws, ws + OFF_QS, ws + OFF_KS);
    k_minmax<<<32, 256, 0, stream>>>(ws + OFF_KS, ws + OFF_KMN, ws + OFF_KMX);
    k_ugemm<<<512, 256, 0, stream>>>(x, ws + OFF_W2, u16);
    k_bias<<<1024, 256, 0, stream>>>(bo, y);
    k_attn<<<512, 256, 0, stream>>>(ws + OFF_QS, ws + OFF_KS, ws + OFF_KMN,
                                    ws + OFF_KMX, u16, y);
}

// Round 3
// 120.683 us; speedup vs baseline: 4.2838x; 1.3524x over previous
//
#include <hip/hip_runtime.h>
#include <math.h>

// Problem constants
#define NB 4
#define NC 2048
#define NH 8
#define NK 128

// exp2-domain logit scale: log2(e)/sqrt(128)
#define A2SCALE (1.4426950408889634f * 0.08838834764831845f)

typedef __attribute__((ext_vector_type(8))) short bf16x8;
typedef __attribute__((ext_vector_type(4))) float f32x4;

// ---------------- ws layout (float offsets) ----------------
// wspart [4][2048]        @ 0        (8192)   e-quarter partials of wq/wk sums
// W2     [8][128][128]    @ 8192     (131072) f32
// qs     [32][2048]       @ 139264
// ks     [32][2048]       @ 204800
// u(bf16)[32][64ig][8nt][64lane][8j] @ 270336 (8.39M ushort)
#define OFF_W2  8192
#define OFF_QS  139264
#define OFF_KS  204800
#define OFF_U   270336

__device__ static inline float exp2_hw(float x) {
#if __has_builtin(__builtin_amdgcn_exp2f)
    return __builtin_amdgcn_exp2f(x);
#else
    float r;
    asm volatile("v_exp_f32 %0, %1\n\ts_nop 1" : "=v"(r) : "v"(x));
    return r;
#endif
}

// pack 2 f32 -> u32 of 2 bf16 (RNE), low half = first arg
__device__ static inline unsigned cvtpk(float lo, float hi) {
    unsigned r;
    asm("v_cvt_pk_bf16_f32 %0, %1, %2" : "=v"(r) : "v"(lo), "v"(hi));
    return r;
}

__device__ static inline bf16x8 pack8(float4 a, float4 b) {
    union { unsigned u[4]; bf16x8 v; } r;
    r.u[0] = cvtpk(a.x, a.y);
    r.u[1] = cvtpk(a.z, a.w);
    r.u[2] = cvtpk(b.x, b.y);
    r.u[3] = cvtpk(b.z, b.w);
    return r.v;
}

// wspart[eq][which*1024+h*128+m] = sum_{e in eq*32..+32} W[h*128+e][m]
// grid 64 x 256  (blk = (which*8+h)*4 + eq)
__global__ __launch_bounds__(256) void k_wsum(const float* __restrict__ Wq,
                                              const float* __restrict__ Wk,
                                              float* __restrict__ wspart) {
    int blk = blockIdx.x;
    int which = blk >> 5, h = (blk >> 2) & 7, eq = blk & 3;
    const float* W = which ? Wk : Wq;
    int m = threadIdx.x & 127, part = threadIdx.x >> 7;
    const float* base = W + (h * 128 + eq * 32 + part * 16) * 128 + m;
    float s = 0.f;
#pragma unroll
    for (int e = 0; e < 16; ++e) s += base[e * 128];
    __shared__ float sp[128];
    if (part) sp[m] = s;
    __syncthreads();
    if (!part) wspart[eq * 2048 + which * 1024 + h * 128 + m] = s + sp[m];
}

// W2[h][kk][m] = sum_e Wv[h*128+e][m] * Wo[kk][h*128+e].  grid 1024 x 128
__global__ __launch_bounds__(128) void k_w2(const float* __restrict__ Wv,
                                            const float* __restrict__ Wo,
                                            float* __restrict__ W2) {
    int h = blockIdx.x >> 7, kk = blockIdx.x & 127;
    __shared__ float wo_s[128];
    int m = threadIdx.x;
    wo_s[m] = Wo[kk * 1024 + h * 128 + m];
    __syncthreads();
    const float* base = Wv + (h * 128) * 128 + m;
    float s = 0.f;
#pragma unroll 4
    for (int e = 0; e < 128; ++e) s += base[e * 128] * wo_s[e];
    W2[(h * 128 + kk) * 128 + m] = s;
}

// qs[bh][t], ks[bh][t].  grid 256 x 256 (32 rows per block)
__global__ __launch_bounds__(256) void k_qsks(const float* __restrict__ x,
                                              const float* __restrict__ wspart,
                                              float* __restrict__ qs,
                                              float* __restrict__ ks) {
    __shared__ float xs[32][129];
    __shared__ float wsum[2048];
    int tid = threadIdx.x;
    for (int j = tid; j < 2048; j += 256)
        wsum[j] = wspart[j] + wspart[2048 + j] + wspart[4096 + j] + wspart[6144 + j];
    int row0 = blockIdx.x * 32;
    for (int j = tid; j < 32 * 128; j += 256) {
        int r = j >> 7, m = j & 127;
        xs[r][m] = x[(size_t)(row0 + r) * 128 + m];
    }
    __syncthreads();
#pragma unroll
    for (int jj = 0; jj < 2; ++jj) {
        int o = tid + 256 * jj;
        int r = o & 31;
        int q = o >> 5;
        int which = q >> 3, h = q & 7;
        const float* wrow = &wsum[which * 1024 + h * 128];
        float s = 0.f;
#pragma unroll 4
        for (int m = 0; m < 128; ++m) s += xs[r][m] * wrow[m];
        int row = row0 + r, b = row >> 11, t = row & 2047;
        float* dst = which ? ks : qs;
        dst[(b * 8 + h) * 2048 + t] = s;
    }
}

// u[bh][i][kk] = sum_m x[b][i][m] * W2[h][kk][m]  via bf16 MFMA, register GEMM.
// Output in u B-frag layout [bh][ig=i>>5][nt=kk>>4][lane][j].  grid 512 x 256
__global__ __launch_bounds__(256) void k_ugemm(const float* __restrict__ x,
                                               const float* __restrict__ W2,
                                               unsigned short* __restrict__ u16) {
    int gid = blockIdx.x;
    int b = gid >> 7, h = (gid >> 4) & 7, it = gid & 15;
    int tid = threadIdx.x;
    int lane = tid & 63, wid = tid >> 6;
    int wr = wid >> 1, wc = wid & 1;
    int l15 = lane & 15, l4 = lane >> 4;

    const float* xb = x + (size_t)(b * 2048 + it * 128) * 128;
    const float* w2h = W2 + h * 16384;

    f32x4 acc[4][4];
#pragma unroll
    for (int m = 0; m < 4; ++m)
#pragma unroll
        for (int n = 0; n < 4; ++n) acc[m][n] = (f32x4)0.f;

#pragma unroll
    for (int mg = 0; mg < 4; ++mg) {
        bf16x8 af[4], bfr[4];
#pragma unroll
        for (int m = 0; m < 4; ++m) {
            const float* src = xb + (wr * 64 + m * 16 + l15) * 128 + mg * 32 + l4 * 8;
            af[m] = pack8(*(const float4*)src, *(const float4*)(src + 4));
        }
#pragma unroll
        for (int n = 0; n < 4; ++n) {
            const float* src = w2h + (wc * 64 + n * 16 + l15) * 128 + mg * 32 + l4 * 8;
            bfr[n] = pack8(*(const float4*)src, *(const float4*)(src + 4));
        }
#pragma unroll
        for (int m = 0; m < 4; ++m)
#pragma unroll
            for (int n = 0; n < 4; ++n)
                acc[m][n] = __builtin_amdgcn_mfma_f32_16x16x32_bf16(
                    af[m], bfr[n], acc[m][n], 0, 0, 0);
    }

    // transpose acc -> u B-frag layout through LDS (32 KB)
    __shared__ unsigned u_sh[8192];
#pragma unroll
    for (int m = 0; m < 4; ++m) {
        int i_base = wr * 64 + m * 16 + l4 * 4;
        int ig = i_base >> 5;
        int lg = 16 * ((i_base >> 3) & 3);
        int jp = (i_base & 7) >> 1;          // 0 or 2
#pragma unroll
        for (int n = 0; n < 4; ++n) {
            int kk = wc * 64 + n * 16 + l15;
            int lp = (kk & 15) + lg;
            int idx = ((ig * 8 + (kk >> 4)) * 64 + lp) * 4 + jp;
            uint2 w;
            w.x = cvtpk(acc[m][n][0], acc[m][n][1]);
            w.y = cvtpk(acc[m][n][2], acc[m][n][3]);
            *(uint2*)&u_sh[idx] = w;
        }
    }
    __syncthreads();
    unsigned short* ub = u16 + ((size_t)(b * 8 + h) * 64 + it * 4) * 4096;
#pragma unroll
    for (int q = 0; q < 8; ++q)
        ((uint4*)ub)[tid + q * 256] = ((const uint4*)u_sh)[tid + q * 256];
}

// init d_out with bias.  grid 1024 x 256, float4
__global__ __launch_bounds__(256) void k_bias(const float* __restrict__ bo,
                                              float* __restrict__ y) {
    int id = blockIdx.x * 256 + threadIdx.x;
    int kk4 = id & 31;
    ((float4*)y)[id] = ((const float4*)bo)[kk4];
}

// attention + output via MFMA: y[b][t][kk] += (1/z_t) sum_i P[t,i] * u[i,kk]
// grid 512 x 256 (bh x 16 t-tiles of 128), XCD-locality mapping.
__global__ __launch_bounds__(256) void k_attn(const float* __restrict__ qs,
                                              const float* __restrict__ ks,
                                              const unsigned short* __restrict__ ub,
                                              float* __restrict__ y) {
    int L = blockIdx.x;
    int xcd = L & 7, slot = L >> 3;
    int bh = xcd * 4 + (slot >> 4);   // 4 bh per XCD -> u slice (2MB bf16) L2-resident
    int tt = slot & 15;
    int b = bh >> 3;
    int t0 = tt * 128;
    int tid = threadIdx.x;
    int lane = tid & 63, wid = tid >> 6;
    int wr = wid >> 1, wc = wid & 1;

    __shared__ uint4 p_lds4[1024];   // P bf16, A-frag layout [hf2][mt8][lane64][j8]
    __shared__ uint4 u_lds4[1024];   // u bf16, B-frag layout [kq2][nt8][lane64][j8]
    __shared__ float kss[2048];
    __shared__ float zp[128][2];
    __shared__ float zs[128];
    __shared__ float red[8];

    for (int j = tid; j < 512; j += 256)
        ((float4*)kss)[j] = ((const float4*)(ks + bh * 2048))[j];
    int t = tid >> 1, hf = tid & 1;    // this thread computes P row t, i-half hf
    float a = qs[bh * 2048 + t0 + t] * A2SCALE;
    __syncthreads();

    // in-block min/max of kss
    float mn = 1e30f, mx = -1e30f;
    {
        const float4* ka = (const float4*)kss;
#pragma unroll
        for (int jj = 0; jj < 2; ++jj) {
            float4 v = ka[tid + jj * 256];
            mn = fminf(mn, fminf(fminf(v.x, v.y), fminf(v.z, v.w)));
            mx = fmaxf(mx, fmaxf(fmaxf(v.x, v.y), fmaxf(v.z, v.w)));
        }
#pragma unroll
        for (int off = 32; off; off >>= 1) {
            mn = fminf(mn, __shfl_xor(mn, off));
            mx = fmaxf(mx, __shfl_xor(mx, off));
        }
        if (!lane) { red[wid] = mn; red[4 + wid] = mx; }
    }
    __syncthreads();
    mn = fminf(fminf(red[0], red[1]), fminf(red[2], red[3]));
    mx = fmaxf(fmaxf(red[4], red[5]), fmaxf(red[6], red[7]));
    float negM = -(a > 0.f ? a * mx : a * mn);   // exact row max (rank-1 logits)
    float zacc = 0.f;

    const unsigned short* gub = ub + (size_t)bh * 64 * 4096;
    f32x4 acc[4][4];
#pragma unroll
    for (int m = 0; m < 4; ++m)
#pragma unroll
        for (int n = 0; n < 4; ++n) acc[m][n] = (f32x4)0.f;

    int pb = (hf * 8 + (t >> 4)) * 64 + (t & 15);   // uint4 index base in p_lds4

    for (int ic = 0; ic < 2048; ic += 64) {
        __syncthreads();   // protect LDS from previous iteration's readers
        // ---- stage u chunk (16 KB, linear) via async global->LDS ----
        {
            const unsigned short* src = gub + (size_t)(ic >> 5) * 4096;
#pragma unroll
            for (int s = 0; s < 4; ++s) {
                int seg = s * 4 + wid;   // wave-uniform
                __builtin_amdgcn_global_load_lds(
                    (const __attribute__((address_space(1))) unsigned int*)(src + seg * 512 + lane * 8),
                    (__attribute__((address_space(3))) unsigned int*)((unsigned short*)u_lds4 + seg * 512),
                    16, 0, 0);
            }
        }
        // ---- compute P tile 128x64 -> bf16 A-frags in LDS ----
        {
            const float4* kp4 = (const float4*)&kss[ic + hf * 32];
            unsigned words[16];
#pragma unroll
            for (int q4 = 0; q4 < 8; ++q4) {
                float4 kv = kp4[q4];
                float e0 = exp2_hw(fmaf(a, kv.x, negM));
                float e1 = exp2_hw(fmaf(a, kv.y, negM));
                float e2 = exp2_hw(fmaf(a, kv.z, negM));
                float e3 = exp2_hw(fmaf(a, kv.w, negM));
                zacc += (e0 + e1) + (e2 + e3);
                words[q4 * 2] = cvtpk(e0, e1);
                words[q4 * 2 + 1] = cvtpk(e2, e3);
            }
#pragma unroll
            for (int g = 0; g < 4; ++g)
                p_lds4[pb + g * 16] =
                    make_uint4(words[4 * g], words[4 * g + 1], words[4 * g + 2], words[4 * g + 3]);
        }
        __syncthreads();   // drains vmcnt (u ready) + lgkm (P ready)
        // ---- MFMA phase: 2 k-steps of 32, 16 mfma each ----
        __builtin_amdgcn_s_setprio(1);
#pragma unroll
        for (int kq = 0; kq < 2; ++kq) {
            bf16x8 af[4], bfr[4];
#pragma unroll
            for (int m = 0; m < 4; ++m)
                af[m] = *(const bf16x8*)&p_lds4[(kq * 8 + wr * 4 + m) * 64 + lane];
#pragma unroll
            for (int n = 0; n < 4; ++n)
                bfr[n] = *(const bf16x8*)&u_lds4[(kq * 8 + wc * 4 + n) * 64 + lane];
#pragma unroll
            for (int m = 0; m < 4; ++m)
#pragma unroll
                for (int n = 0; n < 4; ++n)
                    acc[m][n] = __builtin_amdgcn_mfma_f32_16x16x32_bf16(
                        af[m], bfr[n], acc[m][n], 0, 0, 0);
        }
        __builtin_amdgcn_s_setprio(0);
    }
    zp[t][hf] = zacc;
    __syncthreads();
    if (tid < 128) zs[tid] = 1.f / (zp[tid][0] + zp[tid][1]);
    __syncthreads();

    // epilogue: C/D layout col=lane&15, row=(lane>>4)*4+reg
    int l16 = lane & 15, l4 = lane >> 4;
#pragma unroll
    for (int m = 0; m < 4; ++m) {
#pragma unroll
        for (int r = 0; r < 4; ++r) {
            int tl = wr * 64 + m * 16 + l4 * 4 + r;
            float zinv = zs[tl];
            float* yrow = y + ((size_t)b * 2048 + t0 + tl) * 128;
#pragma unroll
            for (int n = 0; n < 4; ++n)
                atomicAdd(&yrow[wc * 64 + n * 16 + l16], acc[m][n][r] * zinv);
        }
    }
}

extern "C" void kernel_launch(void* const* d_in, const int* in_sizes, int n_in,
                              void* d_out, int out_size, void* d_ws, size_t ws_size,
                              hipStream_t stream) {
    const float* x  = (const float*)d_in[0];
    const float* Wq = (const float*)d_in[1];
    const float* Wk = (const float*)d_in[2];
    const float* Wv = (const float*)d_in[3];
    const float* Wo = (const float*)d_in[4];
    const float* bo = (const float*)d_in[5];
    float* y  = (float*)d_out;
    float* ws = (float*)d_ws;
    (void)in_sizes; (void)n_in; (void)out_size; (void)ws_size;

    unsigned short* u16 = (unsigned short*)(ws + OFF_U);

    k_wsum<<<64, 256, 0, stream>>>(Wq, Wk, ws);
    k_w2<<<1024, 128, 0, stream>>>(Wv, Wo, ws + OFF_W2);
    k_qsks<<<256, 256, 0, stream>>>(x, ws, ws + OFF_QS, ws + OFF_KS);
    k_ugemm<<<512, 256, 0, stream>>>(x, ws + OFF_W2, u16);
    k_bias<<<1024, 256, 0, stream>>>(bo, y);
    k_attn<<<512, 256, 0, stream>>>(ws + OFF_QS, ws + OFF_KS, u16, y);
}

// Round 4
// 119.988 us; speedup vs baseline: 4.3086x; 1.0058x over previous
//
#include <hip/hip_runtime.h>
#include <math.h>

// Problem constants
#define NB 4
#define NC 2048
#define NH 8
#define NK 128

// exp2-domain logit scale: log2(e)/sqrt(128)
#define A2SCALE (1.4426950408889634f * 0.08838834764831845f)

typedef __attribute__((ext_vector_type(8))) short bf16x8;
typedef __attribute__((ext_vector_type(4))) float f32x4;

// ---------------- ws layout (float offsets) ----------------
// wspart [4][2048]        @ 0        (8192)   e-quarter partials of wq/wk sums
// W2     [8][128][128]    @ 8192     (131072) f32
// qs     [32][2048]       @ 139264
// ks     [32][2048]       @ 204800
// u(bf16)[32][64ig][8nt][64lane][8j] @ 270336 (8.39M ushort)
#define OFF_W2  8192
#define OFF_QS  139264
#define OFF_KS  204800
#define OFF_U   270336

__device__ static inline float exp2_hw(float x) {
#if __has_builtin(__builtin_amdgcn_exp2f)
    return __builtin_amdgcn_exp2f(x);
#else
    float r;
    asm volatile("v_exp_f32 %0, %1\n\ts_nop 1" : "=v"(r) : "v"(x));
    return r;
#endif
}

// pack 2 f32 -> u32 of 2 bf16 (RNE), low half = first arg
__device__ static inline unsigned cvtpk(float lo, float hi) {
    unsigned r;
    asm("v_cvt_pk_bf16_f32 %0, %1, %2" : "=v"(r) : "v"(lo), "v"(hi));
    return r;
}

__device__ static inline bf16x8 pack8(float4 a, float4 b) {
    union { unsigned u[4]; bf16x8 v; } r;
    r.u[0] = cvtpk(a.x, a.y);
    r.u[1] = cvtpk(a.z, a.w);
    r.u[2] = cvtpk(b.x, b.y);
    r.u[3] = cvtpk(b.z, b.w);
    return r.v;
}

// wspart[eq][which*1024+h*128+m] = sum_{e in eq*32..+32} W[h*128+e][m]
// grid 64 x 256  (blk = (which*8+h)*4 + eq)
__global__ __launch_bounds__(256) void k_wsum(const float* __restrict__ Wq,
                                              const float* __restrict__ Wk,
                                              float* __restrict__ wspart) {
    int blk = blockIdx.x;
    int which = blk >> 5, h = (blk >> 2) & 7, eq = blk & 3;
    const float* W = which ? Wk : Wq;
    int m = threadIdx.x & 127, part = threadIdx.x >> 7;
    const float* base = W + (h * 128 + eq * 32 + part * 16) * 128 + m;
    float s = 0.f;
#pragma unroll
    for (int e = 0; e < 16; ++e) s += base[e * 128];
    __shared__ float sp[128];
    if (part) sp[m] = s;
    __syncthreads();
    if (!part) wspart[eq * 2048 + which * 1024 + h * 128 + m] = s + sp[m];
}

// W2[h][kk][m] = sum_e Wv[h*128+e][m] * Wo[kk][h*128+e].  grid 1024 x 128
__global__ __launch_bounds__(128) void k_w2(const float* __restrict__ Wv,
                                            const float* __restrict__ Wo,
                                            float* __restrict__ W2) {
    int h = blockIdx.x >> 7, kk = blockIdx.x & 127;
    __shared__ float wo_s[128];
    int m = threadIdx.x;
    wo_s[m] = Wo[kk * 1024 + h * 128 + m];
    __syncthreads();
    const float* base = Wv + (h * 128) * 128 + m;
    float s = 0.f;
#pragma unroll 4
    for (int e = 0; e < 128; ++e) s += base[e * 128] * wo_s[e];
    W2[(h * 128 + kk) * 128 + m] = s;
}

// qs[bh][t], ks[bh][t].  grid 256 x 256 (32 rows per block)
__global__ __launch_bounds__(256) void k_qsks(const float* __restrict__ x,
                                              const float* __restrict__ wspart,
                                              float* __restrict__ qs,
                                              float* __restrict__ ks) {
    __shared__ float xs[32][129];
    __shared__ float wsum[2048];
    int tid = threadIdx.x;
    for (int j = tid; j < 2048; j += 256)
        wsum[j] = wspart[j] + wspart[2048 + j] + wspart[4096 + j] + wspart[6144 + j];
    int row0 = blockIdx.x * 32;
    for (int j = tid; j < 32 * 128; j += 256) {
        int r = j >> 7, m = j & 127;
        xs[r][m] = x[(size_t)(row0 + r) * 128 + m];
    }
    __syncthreads();
#pragma unroll
    for (int jj = 0; jj < 2; ++jj) {
        int o = tid + 256 * jj;
        int r = o & 31;
        int q = o >> 5;
        int which = q >> 3, h = q & 7;
        const float* wrow = &wsum[which * 1024 + h * 128];
        float s = 0.f;
#pragma unroll 4
        for (int m = 0; m < 128; ++m) s += xs[r][m] * wrow[m];
        int row = row0 + r, b = row >> 11, t = row & 2047;
        float* dst = which ? ks : qs;
        dst[(b * 8 + h) * 2048 + t] = s;
    }
}

// u[bh][i][kk] = sum_m x[b][i][m] * W2[h][kk][m]  via bf16 MFMA, register GEMM.
// Output in u B-frag layout [bh][ig=i>>5][nt=kk>>4][lane][j].  grid 512 x 256
__global__ __launch_bounds__(256) void k_ugemm(const float* __restrict__ x,
                                               const float* __restrict__ W2,
                                               unsigned short* __restrict__ u16) {
    int gid = blockIdx.x;
    int b = gid >> 7, h = (gid >> 4) & 7, it = gid & 15;
    int tid = threadIdx.x;
    int lane = tid & 63, wid = tid >> 6;
    int wr = wid >> 1, wc = wid & 1;
    int l15 = lane & 15, l4 = lane >> 4;

    const float* xb = x + (size_t)(b * 2048 + it * 128) * 128;
    const float* w2h = W2 + h * 16384;

    f32x4 acc[4][4];
#pragma unroll
    for (int m = 0; m < 4; ++m)
#pragma unroll
        for (int n = 0; n < 4; ++n) acc[m][n] = (f32x4)0.f;

#pragma unroll
    for (int mg = 0; mg < 4; ++mg) {
        bf16x8 af[4], bfr[4];
#pragma unroll
        for (int m = 0; m < 4; ++m) {
            const float* src = xb + (wr * 64 + m * 16 + l15) * 128 + mg * 32 + l4 * 8;
            af[m] = pack8(*(const float4*)src, *(const float4*)(src + 4));
        }
#pragma unroll
        for (int n = 0; n < 4; ++n) {
            const float* src = w2h + (wc * 64 + n * 16 + l15) * 128 + mg * 32 + l4 * 8;
            bfr[n] = pack8(*(const float4*)src, *(const float4*)(src + 4));
        }
#pragma unroll
        for (int m = 0; m < 4; ++m)
#pragma unroll
            for (int n = 0; n < 4; ++n)
                acc[m][n] = __builtin_amdgcn_mfma_f32_16x16x32_bf16(
                    af[m], bfr[n], acc[m][n], 0, 0, 0);
    }

    // transpose acc -> u B-frag layout through LDS (32 KB)
    __shared__ unsigned u_sh[8192];
#pragma unroll
    for (int m = 0; m < 4; ++m) {
        int i_base = wr * 64 + m * 16 + l4 * 4;
        int ig = i_base >> 5;
        int lg = 16 * ((i_base >> 3) & 3);
        int jp = (i_base & 7) >> 1;          // 0 or 2
#pragma unroll
        for (int n = 0; n < 4; ++n) {
            int kk = wc * 64 + n * 16 + l15;
            int lp = (kk & 15) + lg;
            int idx = ((ig * 8 + (kk >> 4)) * 64 + lp) * 4 + jp;
            uint2 w;
            w.x = cvtpk(acc[m][n][0], acc[m][n][1]);
            w.y = cvtpk(acc[m][n][2], acc[m][n][3]);
            *(uint2*)&u_sh[idx] = w;
        }
    }
    __syncthreads();
    unsigned short* ub = u16 + ((size_t)(b * 8 + h) * 64 + it * 4) * 4096;
#pragma unroll
    for (int q = 0; q < 8; ++q)
        ((uint4*)ub)[tid + q * 256] = ((const uint4*)u_sh)[tid + q * 256];
}

// init d_out with bias.  grid 1024 x 256, float4
__global__ __launch_bounds__(256) void k_bias(const float* __restrict__ bo,
                                              float* __restrict__ y) {
    int id = blockIdx.x * 256 + threadIdx.x;
    int kk4 = id & 31;
    ((float4*)y)[id] = ((const float4*)bo)[kk4];
}

// attention + output via MFMA: y[b][t][kk] += (1/z_t) sum_i P[t,i] * u[i,kk]
// grid 512 x 256 (bh x 16 t-tiles of 128), XCD-locality mapping.
// u: global->register (B-frag order), double-buffered, prefetched 1 chunk ahead.
// P: LDS double-buffer, ONE raw barrier per 64-i chunk (lgkm-only drain).
__global__ __launch_bounds__(256, 2) void k_attn(const float* __restrict__ qs,
                                                 const float* __restrict__ ks,
                                                 const unsigned short* __restrict__ ub,
                                                 float* __restrict__ y) {
    int L = blockIdx.x;
    int xcd = L & 7, slot = L >> 3;
    int bh = xcd * 4 + (slot >> 4);   // 4 bh per XCD -> u slice (2MB bf16) L2-resident
    int tt = slot & 15;
    int b = bh >> 3;
    int t0 = tt * 128;
    int tid = threadIdx.x;
    int lane = tid & 63, wid = tid >> 6;
    int wr = wid >> 1, wc = wid & 1;

    __shared__ uint4 p_lds4[2048];   // 2 bufs x P bf16 A-frag [hf2][mt8][lane64][j8]
    __shared__ float kss[2048];
    __shared__ float zp[128][2];
    __shared__ float zs[128];
    __shared__ float red[8];

    for (int j = tid; j < 512; j += 256)
        ((float4*)kss)[j] = ((const float4*)(ks + bh * 2048))[j];
    int t = tid >> 1, hf = tid & 1;    // this thread computes P row t, i-half hf
    float a = qs[bh * 2048 + t0 + t] * A2SCALE;
    __syncthreads();

    // in-block min/max of kss
    float mn = 1e30f, mx = -1e30f;
    {
        const float4* ka = (const float4*)kss;
#pragma unroll
        for (int jj = 0; jj < 2; ++jj) {
            float4 v = ka[tid + jj * 256];
            mn = fminf(mn, fminf(fminf(v.x, v.y), fminf(v.z, v.w)));
            mx = fmaxf(mx, fmaxf(fmaxf(v.x, v.y), fmaxf(v.z, v.w)));
        }
#pragma unroll
        for (int off = 32; off; off >>= 1) {
            mn = fminf(mn, __shfl_xor(mn, off));
            mx = fmaxf(mx, __shfl_xor(mx, off));
        }
        if (!lane) { red[wid] = mn; red[4 + wid] = mx; }
    }
    __syncthreads();
    mn = fminf(fminf(red[0], red[1]), fminf(red[2], red[3]));
    mx = fmaxf(fmaxf(red[4], red[5]), fmaxf(red[6], red[7]));
    float negM = -(a > 0.f ? a * mx : a * mn);   // exact row max (rank-1 logits)
    float zacc = 0.f;

    const unsigned short* gub = ub + (size_t)bh * 64 * 4096;
    f32x4 acc[4][4];
#pragma unroll
    for (int m = 0; m < 4; ++m)
#pragma unroll
        for (int n = 0; n < 4; ++n) acc[m][n] = (f32x4)0.f;

    int pb = (hf * 8 + (t >> 4)) * 64 + (t & 15);   // uint4 index base in p_lds4

    // u register fragments, double-buffered (static indexing only)
    bf16x8 uA[8], uB[8];

#define ULOAD(dst, icv) do {                                                   \
    int ig0_ = (icv) >> 5;                                                     \
    _Pragma("unroll")                                                          \
    for (int kq_ = 0; kq_ < 2; ++kq_)                                          \
        _Pragma("unroll")                                                      \
        for (int n_ = 0; n_ < 4; ++n_)                                         \
            dst[kq_ * 4 + n_] = *(const bf16x8*)(gub +                         \
                (size_t)((ig0_ + kq_) * 8 + wc * 4 + n_) * 512 + lane * 8);    \
} while (0)

    auto pcompute = [&](int ic, int buf) {
        const float4* kp4 = (const float4*)&kss[ic + hf * 32];
        unsigned words[16];
#pragma unroll
        for (int q4 = 0; q4 < 8; ++q4) {
            float4 kv = kp4[q4];
            float e0 = exp2_hw(fmaf(a, kv.x, negM));
            float e1 = exp2_hw(fmaf(a, kv.y, negM));
            float e2 = exp2_hw(fmaf(a, kv.z, negM));
            float e3 = exp2_hw(fmaf(a, kv.w, negM));
            zacc += (e0 + e1) + (e2 + e3);
            words[q4 * 2] = cvtpk(e0, e1);
            words[q4 * 2 + 1] = cvtpk(e2, e3);
        }
        uint4* pd = &p_lds4[buf * 1024 + pb];
#pragma unroll
        for (int g = 0; g < 4; ++g)
            pd[g * 16] = make_uint4(words[4 * g], words[4 * g + 1],
                                    words[4 * g + 2], words[4 * g + 3]);
    };

    auto domfma = [&](int buf, bf16x8* u8) {
        __builtin_amdgcn_s_setprio(1);
#pragma unroll
        for (int kq = 0; kq < 2; ++kq) {
            bf16x8 af[4];
#pragma unroll
            for (int m = 0; m < 4; ++m)
                af[m] = *(const bf16x8*)&p_lds4[buf * 1024 + (kq * 8 + wr * 4 + m) * 64 + lane];
#pragma unroll
            for (int m = 0; m < 4; ++m)
#pragma unroll
                for (int n = 0; n < 4; ++n)
                    acc[m][n] = __builtin_amdgcn_mfma_f32_16x16x32_bf16(
                        af[m], u8[kq * 4 + n], acc[m][n], 0, 0, 0);
        }
        __builtin_amdgcn_s_setprio(0);
    };

#define BAR() do {                                              \
    asm volatile("s_waitcnt lgkmcnt(0)" ::: "memory");          \
    __builtin_amdgcn_sched_barrier(0);                          \
    __builtin_amdgcn_s_barrier();                               \
} while (0)

    ULOAD(uA, 0);
    for (int ic = 0; ic < 2048; ic += 128) {
        pcompute(ic, 0);
        ULOAD(uB, ic + 64);
        BAR();
        domfma(0, uA);

        pcompute(ic + 64, 1);
        {
            int icn = (ic + 128 < 2048) ? ic + 128 : 0;   // tail: harmless reload
            ULOAD(uA, icn);
        }
        BAR();
        domfma(1, uB);
    }
#undef ULOAD
#undef BAR

    __syncthreads();
    zp[t][hf] = zacc;
    __syncthreads();
    if (tid < 128) zs[tid] = 1.f / (zp[tid][0] + zp[tid][1]);
    __syncthreads();

    // epilogue: C/D layout col=lane&15, row=(lane>>4)*4+reg
    int l16 = lane & 15, l4 = lane >> 4;
#pragma unroll
    for (int m = 0; m < 4; ++m) {
#pragma unroll
        for (int r = 0; r < 4; ++r) {
            int tl = wr * 64 + m * 16 + l4 * 4 + r;
            float zinv = zs[tl];
            float* yrow = y + ((size_t)b * 2048 + t0 + tl) * 128;
#pragma unroll
            for (int n = 0; n < 4; ++n)
                atomicAdd(&yrow[wc * 64 + n * 16 + l16], acc[m][n][r] * zinv);
        }
    }
}

extern "C" void kernel_launch(void* const* d_in, const int* in_sizes, int n_in,
                              void* d_out, int out_size, void* d_ws, size_t ws_size,
                              hipStream_t stream) {
    const float* x  = (const float*)d_in[0];
    const float* Wq = (const float*)d_in[1];
    const float* Wk = (const float*)d_in[2];
    const float* Wv = (const float*)d_in[3];
    const float* Wo = (const float*)d_in[4];
    const float* bo = (const float*)d_in[5];
    float* y  = (float*)d_out;
    float* ws = (float*)d_ws;
    (void)in_sizes; (void)n_in; (void)out_size; (void)ws_size;

    unsigned short* u16 = (unsigned short*)(ws + OFF_U);

    k_wsum<<<64, 256, 0, stream>>>(Wq, Wk, ws);
    k_w2<<<1024, 128, 0, stream>>>(Wv, Wo, ws + OFF_W2);
    k_qsks<<<256, 256, 0, stream>>>(x, ws, ws + OFF_QS, ws + OFF_KS);
    k_ugemm<<<512, 256, 0, stream>>>(x, ws + OFF_W2, u16);
    k_bias<<<1024, 256, 0, stream>>>(bo, y);
    k_attn<<<512, 256, 0, stream>>>(ws + OFF_QS, ws + OFF_KS, u16, y);
}

// Round 5
// 113.810 us; speedup vs baseline: 4.5425x; 1.0543x over previous
//
#include <hip/hip_runtime.h>
#include <math.h>

// Problem constants
#define NB 4
#define NC 2048
#define NH 8
#define NK 128

// exp2-domain logit scale: log2(e)/sqrt(128)
#define A2SCALE (1.4426950408889634f * 0.08838834764831845f)

typedef __attribute__((ext_vector_type(8))) short bf16x8;
typedef __attribute__((ext_vector_type(4))) float f32x4;

// ---------------- ws layout (float offsets) ----------------
// wspart [4][2048]        @ 0        (8192)   e-quarter partials of wq/wk sums
// W2     [8][128][128]    @ 8192     (131072) f32
// qs     [32][2048]       @ 139264
// ks     [32][2048]       @ 204800
// u(bf16)[32][64ig][8nt][64lane][8j] @ 270336 (8.39M ushort)
#define OFF_W2  8192
#define OFF_QS  139264
#define OFF_KS  204800
#define OFF_U   270336

__device__ static inline float exp2_hw(float x) {
#if __has_builtin(__builtin_amdgcn_exp2f)
    return __builtin_amdgcn_exp2f(x);
#else
    float r;
    asm volatile("v_exp_f32 %0, %1\n\ts_nop 1" : "=v"(r) : "v"(x));
    return r;
#endif
}

// pack 2 f32 -> u32 of 2 bf16 (RNE), low half = first arg
__device__ static inline unsigned cvtpk(float lo, float hi) {
    unsigned r;
    asm("v_cvt_pk_bf16_f32 %0, %1, %2" : "=v"(r) : "v"(lo), "v"(hi));
    return r;
}

__device__ static inline bf16x8 pack8(float4 a, float4 b) {
    union { unsigned u[4]; bf16x8 v; } r;
    r.u[0] = cvtpk(a.x, a.y);
    r.u[1] = cvtpk(a.z, a.w);
    r.u[2] = cvtpk(b.x, b.y);
    r.u[3] = cvtpk(b.z, b.w);
    return r.v;
}

// wspart[eq][which*1024+h*128+m] = sum_{e in eq*32..+32} W[h*128+e][m]
// Also initializes y = bias (fused former k_bias).  grid 64 x 256
__global__ __launch_bounds__(256) void k_wsum(const float* __restrict__ Wq,
                                              const float* __restrict__ Wk,
                                              float* __restrict__ wspart,
                                              const float* __restrict__ bo,
                                              float* __restrict__ y) {
    int blk = blockIdx.x;
    int which = blk >> 5, h = (blk >> 2) & 7, eq = blk & 3;
    const float* W = which ? Wk : Wq;
    int m = threadIdx.x & 127, part = threadIdx.x >> 7;
    const float* base = W + (h * 128 + eq * 32 + part * 16) * 128 + m;
    float s = 0.f;
#pragma unroll
    for (int e = 0; e < 16; ++e) s += base[e * 128];
    __shared__ float sp[128];
    if (part) sp[m] = s;
    __syncthreads();
    if (!part) wspart[eq * 2048 + which * 1024 + h * 128 + m] = s + sp[m];

    // y init: 262144 float4s over 64 blocks = 4096/block
    int base4 = blk * 4096 + threadIdx.x;
#pragma unroll
    for (int q = 0; q < 16; ++q) {
        int id = base4 + q * 256;
        ((float4*)y)[id] = ((const float4*)bo)[id & 31];
    }
}

// W2[h][kk][m] = sum_e Wv[h*128+e][m] * Wo[kk][h*128+e].  grid 1024 x 128
__global__ __launch_bounds__(128) void k_w2(const float* __restrict__ Wv,
                                            const float* __restrict__ Wo,
                                            float* __restrict__ W2) {
    int h = blockIdx.x >> 7, kk = blockIdx.x & 127;
    __shared__ float wo_s[128];
    int m = threadIdx.x;
    wo_s[m] = Wo[kk * 1024 + h * 128 + m];
    __syncthreads();
    const float* base = Wv + (h * 128) * 128 + m;
    float s = 0.f;
#pragma unroll 4
    for (int e = 0; e < 128; ++e) s += base[e * 128] * wo_s[e];
    W2[(h * 128 + kk) * 128 + m] = s;
}

// qs[bh][t], ks[bh][t].  grid 256 x 256 (32 rows per block)
__global__ __launch_bounds__(256) void k_qsks(const float* __restrict__ x,
                                              const float* __restrict__ wspart,
                                              float* __restrict__ qs,
                                              float* __restrict__ ks) {
    __shared__ float xs[32][129];
    __shared__ float wsum[2048];
    int tid = threadIdx.x;
    for (int j = tid; j < 2048; j += 256)
        wsum[j] = wspart[j] + wspart[2048 + j] + wspart[4096 + j] + wspart[6144 + j];
    int row0 = blockIdx.x * 32;
    for (int j = tid; j < 32 * 128; j += 256) {
        int r = j >> 7, m = j & 127;
        xs[r][m] = x[(size_t)(row0 + r) * 128 + m];
    }
    __syncthreads();
#pragma unroll
    for (int jj = 0; jj < 2; ++jj) {
        int o = tid + 256 * jj;
        int r = o & 31;
        int q = o >> 5;
        int which = q >> 3, h = q & 7;
        const float* wrow = &wsum[which * 1024 + h * 128];
        float s = 0.f;
#pragma unroll 4
        for (int m = 0; m < 128; ++m) s += xs[r][m] * wrow[m];
        int row = row0 + r, b = row >> 11, t = row & 2047;
        float* dst = which ? ks : qs;
        dst[(b * 8 + h) * 2048 + t] = s;
    }
}

// u[bh][i][kk] = sum_m x[b][i][m] * W2[h][kk][m]  via bf16 MFMA, register GEMM.
// Output in u B-frag layout [bh][ig=i>>5][nt=kk>>4][lane][j].  grid 512 x 256
__global__ __launch_bounds__(256) void k_ugemm(const float* __restrict__ x,
                                               const float* __restrict__ W2,
                                               unsigned short* __restrict__ u16) {
    int gid = blockIdx.x;
    int b = gid >> 7, h = (gid >> 4) & 7, it = gid & 15;
    int tid = threadIdx.x;
    int lane = tid & 63, wid = tid >> 6;
    int wr = wid >> 1, wc = wid & 1;
    int l15 = lane & 15, l4 = lane >> 4;

    const float* xb = x + (size_t)(b * 2048 + it * 128) * 128;
    const float* w2h = W2 + h * 16384;

    f32x4 acc[4][4];
#pragma unroll
    for (int m = 0; m < 4; ++m)
#pragma unroll
        for (int n = 0; n < 4; ++n) acc[m][n] = (f32x4)0.f;

#pragma unroll
    for (int mg = 0; mg < 4; ++mg) {
        bf16x8 af[4], bfr[4];
#pragma unroll
        for (int m = 0; m < 4; ++m) {
            const float* src = xb + (wr * 64 + m * 16 + l15) * 128 + mg * 32 + l4 * 8;
            af[m] = pack8(*(const float4*)src, *(const float4*)(src + 4));
        }
#pragma unroll
        for (int n = 0; n < 4; ++n) {
            const float* src = w2h + (wc * 64 + n * 16 + l15) * 128 + mg * 32 + l4 * 8;
            bfr[n] = pack8(*(const float4*)src, *(const float4*)(src + 4));
        }
#pragma unroll
        for (int m = 0; m < 4; ++m)
#pragma unroll
            for (int n = 0; n < 4; ++n)
                acc[m][n] = __builtin_amdgcn_mfma_f32_16x16x32_bf16(
                    af[m], bfr[n], acc[m][n], 0, 0, 0);
    }

    // transpose acc -> u B-frag layout through LDS (32 KB)
    __shared__ unsigned u_sh[8192];
#pragma unroll
    for (int m = 0; m < 4; ++m) {
        int i_base = wr * 64 + m * 16 + l4 * 4;
        int ig = i_base >> 5;
        int lg = 16 * ((i_base >> 3) & 3);
        int jp = (i_base & 7) >> 1;          // 0 or 2
#pragma unroll
        for (int n = 0; n < 4; ++n) {
            int kk = wc * 64 + n * 16 + l15;
            int lp = (kk & 15) + lg;
            int idx = ((ig * 8 + (kk >> 4)) * 64 + lp) * 4 + jp;
            uint2 w;
            w.x = cvtpk(acc[m][n][0], acc[m][n][1]);
            w.y = cvtpk(acc[m][n][2], acc[m][n][3]);
            *(uint2*)&u_sh[idx] = w;
        }
    }
    __syncthreads();
    unsigned short* ub = u16 + ((size_t)(b * 8 + h) * 64 + it * 4) * 4096;
#pragma unroll
    for (int q = 0; q < 8; ++q)
        ((uint4*)ub)[tid + q * 256] = ((const uint4*)u_sh)[tid + q * 256];
}

// attention + output via MFMA: y[b][t][kk] += (1/z_t) sum_i P[t,i] * u[i,kk]
// grid 1024 x 256: 32 bh x 32 t-tiles of 64 -> 4 blocks/CU (16 waves/CU).
// Waves 2x2 over 64t x 128kk. u global->register (single buf, loaded with
// pcompute as slack). P 64x64 chunk, LDS double-buffered, 1 barrier/chunk.
__global__ __launch_bounds__(256, 4) void k_attn(const float* __restrict__ qs,
                                                 const float* __restrict__ ks,
                                                 const unsigned short* __restrict__ ub,
                                                 float* __restrict__ y) {
    int L = blockIdx.x;
    int xcd = L & 7, slot = L >> 3;
    int bh = xcd * 4 + (slot >> 5);   // 4 bh per XCD -> u slice (2MB bf16) L2-resident
    int tt = slot & 31;
    int b = bh >> 3;
    int t0 = tt * 64;
    int tid = threadIdx.x;
    int lane = tid & 63, wid = tid >> 6;
    int wr = wid >> 1, wc = wid & 1;

    __shared__ uint4 p_lds4[1024];   // 2 bufs x 8 frag-groups x 64 lanes (16 KB)
    __shared__ float kss[2048];
    __shared__ float zp[64][4];
    __shared__ float zs[64];
    __shared__ float red[8];

    for (int j = tid; j < 512; j += 256)
        ((float4*)kss)[j] = ((const float4*)(ks + bh * 2048))[j];
    int t = tid >> 2, c = tid & 3;    // thread: P row t, i-16-chunk c
    float a = qs[bh * 2048 + t0 + t] * A2SCALE;
    __syncthreads();

    // in-block min/max of kss
    float mn = 1e30f, mx = -1e30f;
    {
        const float4* ka = (const float4*)kss;
#pragma unroll
        for (int jj = 0; jj < 2; ++jj) {
            float4 v = ka[tid + jj * 256];
            mn = fminf(mn, fminf(fminf(v.x, v.y), fminf(v.z, v.w)));
            mx = fmaxf(mx, fmaxf(fmaxf(v.x, v.y), fmaxf(v.z, v.w)));
        }
#pragma unroll
        for (int off = 32; off; off >>= 1) {
            mn = fminf(mn, __shfl_xor(mn, off));
            mx = fmaxf(mx, __shfl_xor(mx, off));
        }
        if (!lane) { red[wid] = mn; red[4 + wid] = mx; }
    }
    __syncthreads();
    mn = fminf(fminf(red[0], red[1]), fminf(red[2], red[3]));
    mx = fmaxf(fmaxf(red[4], red[5]), fmaxf(red[6], red[7]));
    float negM = -(a > 0.f ? a * mx : a * mn);   // exact row max (rank-1 logits)
    float zacc = 0.f;

    const unsigned short* gub = ub + (size_t)bh * 64 * 4096;
    f32x4 acc[2][4];
#pragma unroll
    for (int m = 0; m < 2; ++m)
#pragma unroll
        for (int n = 0; n < 4; ++n) acc[m][n] = (f32x4)0.f;

    // P writer indices: frag-group g = (kq=c>>1)*4 + (t>>4); lanes (c&1)*2+s
    int pg = (c >> 1) * 4 + (t >> 4);
    int pl = ((c & 1) * 2) * 16 + (t & 15);

    bf16x8 u8[8];

#define ULOAD(icv) do {                                                        \
    int ig0_ = (icv) >> 5;                                                     \
    _Pragma("unroll")                                                          \
    for (int kq_ = 0; kq_ < 2; ++kq_)                                          \
        _Pragma("unroll")                                                      \
        for (int n_ = 0; n_ < 4; ++n_)                                         \
            u8[kq_ * 4 + n_] = *(const bf16x8*)(gub +                          \
                (size_t)((ig0_ + kq_) * 8 + wc * 4 + n_) * 512 + lane * 8);    \
} while (0)

    auto pcompute = [&](int ic, int buf) {
        const float4* kp4 = (const float4*)&kss[ic + c * 16];
        unsigned words[8];
#pragma unroll
        for (int q4 = 0; q4 < 4; ++q4) {
            float4 kv = kp4[q4];
            float e0 = exp2_hw(fmaf(a, kv.x, negM));
            float e1 = exp2_hw(fmaf(a, kv.y, negM));
            float e2 = exp2_hw(fmaf(a, kv.z, negM));
            float e3 = exp2_hw(fmaf(a, kv.w, negM));
            zacc += (e0 + e1) + (e2 + e3);
            words[q4 * 2] = cvtpk(e0, e1);
            words[q4 * 2 + 1] = cvtpk(e2, e3);
        }
        uint4* pd = &p_lds4[buf * 512 + pg * 64 + pl];
        pd[0] = make_uint4(words[0], words[1], words[2], words[3]);
        pd[16] = make_uint4(words[4], words[5], words[6], words[7]);
    };

    auto domfma = [&](int buf) {
        __builtin_amdgcn_s_setprio(1);
#pragma unroll
        for (int kq = 0; kq < 2; ++kq) {
            bf16x8 af[2];
#pragma unroll
            for (int m = 0; m < 2; ++m)
                af[m] = *(const bf16x8*)&p_lds4[buf * 512 + (kq * 4 + wr * 2 + m) * 64 + lane];
#pragma unroll
            for (int m = 0; m < 2; ++m)
#pragma unroll
                for (int n = 0; n < 4; ++n)
                    acc[m][n] = __builtin_amdgcn_mfma_f32_16x16x32_bf16(
                        af[m], u8[kq * 4 + n], acc[m][n], 0, 0, 0);
        }
        __builtin_amdgcn_s_setprio(0);
    };

#define BAR() do {                                              \
    asm volatile("s_waitcnt lgkmcnt(0)" ::: "memory");          \
    __builtin_amdgcn_sched_barrier(0);                          \
    __builtin_amdgcn_s_barrier();                               \
} while (0)

    for (int ic = 0; ic < 2048; ic += 128) {
        ULOAD(ic);
        pcompute(ic, 0);
        BAR();
        domfma(0);

        ULOAD(ic + 64);
        pcompute(ic + 64, 1);
        BAR();
        domfma(1);
    }
#undef ULOAD
#undef BAR

    __syncthreads();
    zp[t][c] = zacc;
    __syncthreads();
    if (tid < 64) zs[tid] = 1.f / (zp[tid][0] + zp[tid][1] + zp[tid][2] + zp[tid][3]);
    __syncthreads();

    // epilogue: C/D layout col=lane&15, row=(lane>>4)*4+reg
    int l16 = lane & 15, l4 = lane >> 4;
#pragma unroll
    for (int m = 0; m < 2; ++m) {
#pragma unroll
        for (int r = 0; r < 4; ++r) {
            int tl = wr * 32 + m * 16 + l4 * 4 + r;
            float zinv = zs[tl];
            float* yrow = y + ((size_t)b * 2048 + t0 + tl) * 128;
#pragma unroll
            for (int n = 0; n < 4; ++n)
                atomicAdd(&yrow[wc * 64 + n * 16 + l16], acc[m][n][r] * zinv);
        }
    }
}

extern "C" void kernel_launch(void* const* d_in, const int* in_sizes, int n_in,
                              void* d_out, int out_size, void* d_ws, size_t ws_size,
                              hipStream_t stream) {
    const float* x  = (const float*)d_in[0];
    const float* Wq = (const float*)d_in[1];
    const float* Wk = (const float*)d_in[2];
    const float* Wv = (const float*)d_in[3];
    const float* Wo = (const float*)d_in[4];
    const float* bo = (const float*)d_in[5];
    float* y  = (float*)d_out;
    float* ws = (float*)d_ws;
    (void)in_sizes; (void)n_in; (void)out_size; (void)ws_size;

    unsigned short* u16 = (unsigned short*)(ws + OFF_U);

    k_wsum<<<64, 256, 0, stream>>>(Wq, Wk, ws, bo, y);
    k_w2<<<1024, 128, 0, stream>>>(Wv, Wo, ws + OFF_W2);
    k_qsks<<<256, 256, 0, stream>>>(x, ws, ws + OFF_QS, ws + OFF_KS);
    k_ugemm<<<512, 256, 0, stream>>>(x, ws + OFF_W2, u16);
    k_attn<<<1024, 256, 0, stream>>>(ws + OFF_QS, ws + OFF_KS, u16, y);
}